// Round 20
// baseline (869.949 us; speedup 1.0000x reference)
//
#include <hip/hip_runtime.h>
#include <math.h>
#include <stdint.h>

namespace {

constexpr int kNCam  = 6;
constexpr int kInCh  = 256;
constexpr int kOutC  = 80;
constexpr int kDB    = 118;   // depth bins
constexpr int kFH    = 32;
constexpr int kFW    = 88;
constexpr int kHW    = kFH * kFW;       // 2816
constexpr int kNPix  = kNCam * kHW;     // 16896
constexpr int kFeatC = kDB + kOutC;     // 198
constexpr int kNX    = 360;
constexpr int kNVox  = kNX * kNX;       // 129600
constexpr int kNPts  = kDB * kNPix;     // 1993728
constexpr int kScanB = (kNVox + 1023) / 1024;  // 127
constexpr int kSegE  = 256;             // entries per SpMM segment-wave
constexpr int kMaxSeg = (kNPts + kSegE - 1) / kSegE;  // 7788

// async global->LDS DMA, 16B per lane. LDS dest must be linear in lane
// (base + lane*16); global src is per-lane. CK-style addrspace casts.
__device__ __forceinline__ void gload16(const float* g, float* l) {
  auto* gg = reinterpret_cast<const __attribute__((address_space(1))) float*>(
      reinterpret_cast<uintptr_t>(g));
  auto* ll = reinterpret_cast<__attribute__((address_space(3))) float*>(
      reinterpret_cast<uintptr_t>(l));
  __builtin_amdgcn_global_load_lds(gg, ll, 16, 0, 0);
}

// ---------------- 4x4 matrix inverses (fp64 cofactor) ----------------
// Geometry decision path is kept ENTIRELY in fp64; passed with absmax 0.0332.
// DO NOT change anything in the geometry/binning path.
__global__ void prep_inverses_kernel(const float* __restrict__ aug,
                                     const float* __restrict__ l2i,
                                     double* __restrict__ invm) {
  const int t = threadIdx.x;
  if (t >= 12) return;
  const float* s = (t < 6) ? (aug + t * 16) : (l2i + (t - 6) * 16);
  double m[16];
#pragma unroll
  for (int i = 0; i < 16; ++i) m[i] = (double)s[i];
  double inv[16];
  inv[0]  =  m[5]*m[10]*m[15] - m[5]*m[11]*m[14] - m[9]*m[6]*m[15] + m[9]*m[7]*m[14] + m[13]*m[6]*m[11] - m[13]*m[7]*m[10];
  inv[4]  = -m[4]*m[10]*m[15] + m[4]*m[11]*m[14] + m[8]*m[6]*m[15] - m[8]*m[7]*m[14] - m[12]*m[6]*m[11] + m[12]*m[7]*m[10];
  inv[8]  =  m[4]*m[9]*m[15]  - m[4]*m[11]*m[13] - m[8]*m[5]*m[15] + m[8]*m[7]*m[13] + m[12]*m[5]*m[11] - m[12]*m[7]*m[9];
  inv[12] = -m[4]*m[9]*m[14]  + m[4]*m[10]*m[13] + m[8]*m[5]*m[14] - m[8]*m[6]*m[13] - m[12]*m[5]*m[10] + m[12]*m[6]*m[9];
  inv[1]  = -m[1]*m[10]*m[15] + m[1]*m[11]*m[14] + m[9]*m[2]*m[15] - m[9]*m[3]*m[14] - m[13]*m[2]*m[11] + m[13]*m[3]*m[10];
  inv[5]  =  m[0]*m[10]*m[15] - m[0]*m[11]*m[14] - m[8]*m[2]*m[15] + m[8]*m[3]*m[14] + m[12]*m[2]*m[11] - m[12]*m[3]*m[10];
  inv[9]  = -m[0]*m[9]*m[15]  + m[0]*m[11]*m[13] + m[8]*m[1]*m[15] - m[8]*m[3]*m[13] - m[12]*m[1]*m[11] + m[12]*m[3]*m[9];
  inv[13] =  m[0]*m[9]*m[14]  - m[0]*m[10]*m[13] - m[8]*m[1]*m[14] + m[8]*m[2]*m[13] + m[12]*m[1]*m[10] - m[12]*m[2]*m[9];
  inv[2]  =  m[1]*m[6]*m[15]  - m[1]*m[7]*m[14]  - m[5]*m[2]*m[15] + m[5]*m[3]*m[14] + m[13]*m[2]*m[7]  - m[13]*m[3]*m[6];
  inv[6]  = -m[0]*m[6]*m[15]  + m[0]*m[7]*m[14]  + m[4]*m[2]*m[15] - m[4]*m[3]*m[14] - m[12]*m[2]*m[7]  + m[12]*m[3]*m[6];
  inv[10] =  m[0]*m[5]*m[15]  - m[0]*m[7]*m[13]  - m[4]*m[1]*m[15] + m[4]*m[3]*m[13] + m[12]*m[1]*m[7]  - m[12]*m[3]*m[5];
  inv[14] = -m[0]*m[5]*m[14]  + m[0]*m[6]*m[13]  + m[4]*m[1]*m[14] - m[4]*m[2]*m[13] - m[12]*m[1]*m[6]  + m[12]*m[2]*m[5];
  inv[3]  = -m[1]*m[6]*m[11]  + m[1]*m[7]*m[10]  + m[5]*m[2]*m[11] - m[5]*m[3]*m[10] - m[9]*m[2]*m[7]   + m[9]*m[3]*m[6];
  inv[7]  =  m[0]*m[6]*m[11]  - m[0]*m[7]*m[10]  - m[4]*m[2]*m[11] + m[4]*m[3]*m[10] + m[8]*m[2]*m[7]   - m[8]*m[3]*m[6];
  inv[11] = -m[0]*m[5]*m[11]  + m[0]*m[7]*m[9]   + m[4]*m[1]*m[11] - m[4]*m[3]*m[9]  - m[8]*m[1]*m[7]   + m[8]*m[3]*m[5];
  inv[15] =  m[0]*m[5]*m[10]  - m[0]*m[6]*m[9]   - m[4]*m[1]*m[10] + m[4]*m[2]*m[9]  + m[8]*m[1]*m[6]   - m[8]*m[2]*m[5];
  const double det = m[0]*inv[0] + m[1]*inv[4] + m[2]*inv[8] + m[3]*inv[12];
  const double id = 1.0 / det;
#pragma unroll
  for (int i = 0; i < 16; ++i) invm[(size_t)t * 16 + i] = inv[i] * id;
}

// ---------------- depthnet weight transpose: wt_t[ic][208] ----------------
__global__ __launch_bounds__(256) void wt_transpose_kernel(
    const float* __restrict__ w, float* __restrict__ wt_t) {
  const int i = blockIdx.x * 256 + threadIdx.x;
  if (i >= 256 * 208) return;
  const int ic = i / 208;
  const int oc = i - ic * 208;
  wt_t[i] = (oc < kFeatC) ? w[oc * kInCh + ic] : 0.f;
}

// ---------------- depthnet 1x1 conv, v3: gload_lds + OCB=16 ----------------
// Summation order per output: ic ascending, fmaf chain -> bit-identical.
__global__ __launch_bounds__(256, 4) void depthnet_v3_kernel(
    const float* __restrict__ img, const float* __restrict__ wt_t,
    const float* __restrict__ bias, float* __restrict__ feat) {
  __shared__ float xs[16 * 512];
  const int tid = threadIdx.x;
  const int p0 = blockIdx.x * 512;       // kNPix % 512 == 0 (33 blocks)
  const int oc0 = blockIdx.y * 16;
  float acc[2][16];
#pragma unroll
  for (int h = 0; h < 2; ++h)
#pragma unroll
    for (int j = 0; j < 16; ++j) acc[h][j] = 0.f;
  for (int ic0 = 0; ic0 < kInCh; ic0 += 16) {
    if (ic0) __syncthreads();
#pragma unroll
    for (int s = 0; s < 8; ++s) {          // 2048 chunks of 16B
      const int j = tid + s * 256;
      const int r = j >> 7;                // 128 chunks per ic row
      const int k = j & 127;
      const int p4 = p0 + k * 4;           // 4-aligned, never straddles a cam
      const int n = p4 / kHW;
      const int hw = p4 - n * kHW;
      gload16(img + ((size_t)(n * kInCh + ic0 + r)) * kHW + hw, &xs[j * 4]);
    }
    __syncthreads();
#pragma unroll
    for (int kk = 0; kk < 16; ++kk) {
      const float xv0 = xs[kk * 512 + tid];
      const float xv1 = xs[kk * 512 + tid + 256];
      const float* wr = wt_t + (size_t)(ic0 + kk) * 208 + oc0;
#pragma unroll
      for (int j = 0; j < 16; ++j) {
        const float wv = wr[j];
        acc[0][j] = fmaf(wv, xv0, acc[0][j]);
        acc[1][j] = fmaf(wv, xv1, acc[1][j]);
      }
    }
  }
#pragma unroll
  for (int hp = 0; hp < 2; ++hp) {
    const int p = p0 + tid + hp * 256;
    const int n = p / kHW;
    const int hw = p - n * kHW;
#pragma unroll
    for (int j = 0; j < 16; ++j) {
      const int oc = oc0 + j;
      if (oc < kFeatC)
        feat[((size_t)n * kFeatC + oc) * kHW + hw] = acc[hp][j] + bias[oc];
    }
  }
}

// ---------------- softmax over depth bins, in place ----------------
__global__ __launch_bounds__(256) void softmax_depth_kernel(float* __restrict__ feat) {
  const int p = blockIdx.x * 256 + threadIdx.x;
  const int n = p / kHW;
  const int hw = p - n * kHW;
  float* base = feat + (size_t)n * kFeatC * kHW + hw;
  float mx = -3.4e38f;
  for (int d = 0; d < kDB; ++d) mx = fmaxf(mx, base[(size_t)d * kHW]);
  float s = 0.f;
  for (int d = 0; d < kDB; ++d) s += expf(base[(size_t)d * kHW] - mx);
  for (int d = 0; d < kDB; ++d) {
    const float e = expf(base[(size_t)d * kHW] - mx);
    base[(size_t)d * kHW] = e / s;
  }
}

// ---------------- ctx -> pixel-major ctx_t[pix][80] ----------------
__global__ __launch_bounds__(256) void ctx_transpose_kernel(
    const float* __restrict__ feat, float* __restrict__ ctx_t) {
  __shared__ float t[32][81];
  const int tid = threadIdx.x;
  const int b0 = blockIdx.x * 32;
  for (int e = tid; e < 32 * kOutC; e += 256) {
    const int c = e >> 5;
    const int q = e & 31;
    const int pix = b0 + q;
    const int n = pix / kHW;
    const int hw = pix - n * kHW;
    t[q][c] = feat[((size_t)n * kFeatC + kDB + c) * kHW + hw];
  }
  __syncthreads();
  for (int e = tid; e < 32 * kOutC; e += 256) {
    const int q = e / kOutC;
    const int c = e - q * kOutC;
    ctx_t[(size_t)(b0 + q) * kOutC + c] = t[q][c];
  }
}

// ---------------- pass A: per-point voxel binning + histogram ----------------
// fp64 chain copied VERBATIM from the passing kernel.
__global__ __launch_bounds__(256) void point_bin_kernel(
    const double* __restrict__ invm, int* __restrict__ point_vox,
    int* __restrict__ counts) {
  const int p = blockIdx.x * 256 + threadIdx.x;
  const int dd = p / kNPix;
  const int pix = p - dd * kNPix;
  const int n = pix / kHW;
  const int hw = pix - n * kHW;
  const int h = hw / kFW;
  const int w = hw - h * kFW;
  const double* A = invm + (size_t)n * 16;
  const double* L = invm + 96 + (size_t)n * 16;
  const double x = (double)(float)((double)w * (703.0 / 87.0));
  const double y = (double)(float)((double)h * (255.0 / 31.0));
  const double d = (double)(1.0f + 0.5f * (float)dd);
  const double p0 = A[0] * x + A[1] * y + A[2]  * d + A[3];
  const double p1 = A[4] * x + A[5] * y + A[6]  * d + A[7];
  const double p2 = A[8] * x + A[9] * y + A[10] * d + A[11];
  const double q0 = p0 * p2, q1 = p1 * p2;
  const double g0 = L[0] * q0 + L[1] * q1 + L[2]  * p2 + L[3];
  const double g1 = L[4] * q0 + L[5] * q1 + L[6]  * p2 + L[7];
  const double g2 = L[8] * q0 + L[9] * q1 + L[10] * p2 + L[11];
  const double off01 = (double)__fsub_rn(-53.85f, 0.15f);
  const double fx = (g0 - off01) / (double)0.3f;
  const double fy = (g1 - off01) / (double)0.3f;
  const double fz = (g2 - (double)(-10.0f)) / (double)20.0f;
  const int gx = (int)fx;
  const int gy = (int)fy;
  const int gz = (int)fz;
  int vox = -1;
  if (gx >= 0 && gx < kNX && gy >= 0 && gy < kNX && gz == 0)
    vox = gx * kNX + gy;
  point_vox[p] = vox;
  if (vox >= 0) atomicAdd(counts + vox, 1);
}

// ---------------- exclusive scan over voxel counts ----------------
__global__ __launch_bounds__(256) void scan_k1(const int* __restrict__ counts,
                                               int* __restrict__ offsets,
                                               int* __restrict__ bsums) {
  __shared__ int sh[256];
  const int t = threadIdx.x;
  const int base = blockIdx.x * 1024 + t * 4;
  int v[4];
  int s = 0;
#pragma unroll
  for (int k = 0; k < 4; ++k) {
    const int i = base + k;
    v[k] = (i < kNVox) ? counts[i] : 0;
    s += v[k];
  }
  sh[t] = s;
  __syncthreads();
  for (int ofs = 1; ofs < 256; ofs <<= 1) {
    const int x = (t >= ofs) ? sh[t - ofs] : 0;
    __syncthreads();
    sh[t] += x;
    __syncthreads();
  }
  const int excl = sh[t] - s;
  if (t == 255) bsums[blockIdx.x] = sh[255];
  int run = excl;
#pragma unroll
  for (int k = 0; k < 4; ++k) {
    const int i = base + k;
    if (i < kNVox) offsets[i] = run;
    run += v[k];
  }
}

__global__ void scan_k2(int* __restrict__ bsums, int* __restrict__ offsets) {
  if (threadIdx.x == 0) {
    int run = 0;
    for (int b = 0; b < kScanB; ++b) {
      const int x = bsums[b];
      bsums[b] = run;
      run += x;
    }
    offsets[kNVox] = run;
  }
}

__global__ __launch_bounds__(256) void scan_k3(int* __restrict__ offsets,
                                               const int* __restrict__ bsums,
                                               int* __restrict__ cursor) {
  const int base = blockIdx.x * 1024 + threadIdx.x * 4;
  const int add = bsums[blockIdx.x];
#pragma unroll
  for (int k = 0; k < 4; ++k) {
    const int i = base + k;
    if (i < kNVox) {
      const int o = offsets[i] + add;
      offsets[i] = o;
      cursor[i] = o;
    }
  }
}

// ---------------- pass B: fill CSR entries (+ per-entry voxel id) ----------------
__global__ __launch_bounds__(256) void fill_kernel(
    const int* __restrict__ point_vox, int* __restrict__ cursor,
    const float* __restrict__ feat, int* __restrict__ epix,
    float* __restrict__ ew, int* __restrict__ evox) {
  const int p = blockIdx.x * 256 + threadIdx.x;
  const int v = point_vox[p];
  if (v < 0) return;
  const int dd = p / kNPix;
  const int pix = p - dd * kNPix;
  const int n = pix / kHW;
  const int hw = pix - n * kHW;
  const int pos = atomicAdd(cursor + v, 1);
  epix[pos] = pix;
  ew[pos] = feat[((size_t)n * kFeatC + dd) * kHW + hw];
  evox[pos] = v;
}

// ---------------- segmented SpMM: one wave per 256-entry segment ----------------
__global__ __launch_bounds__(256) void spmm_seg_kernel(
    const int* __restrict__ off, const int* __restrict__ evox,
    const int* __restrict__ epix, const float* __restrict__ ew,
    const float* __restrict__ ctx_t, float* __restrict__ pooled) {
  const int wid = (blockIdx.x * 256 + threadIdx.x) >> 6;
  const int lane = threadIdx.x & 63;
  const int nnz = off[kNVox];
  const int s0 = wid * kSegE;
  if (s0 >= nnz) return;
  const int s1 = min(s0 + kSegE, nnz);
  int e = s0;
  int v = evox[e];
  float a0 = 0.f, a1 = 0.f;
  while (e < s1) {
    if (e + 3 < s1 && evox[e + 3] == v) {   // non-decreasing -> e..e+3 all v
      const int px0 = epix[e], px1 = epix[e + 1];
      const int px2 = epix[e + 2], px3 = epix[e + 3];
      const float w0 = ew[e], w1 = ew[e + 1], w2 = ew[e + 2], w3 = ew[e + 3];
      const float* c0 = ctx_t + (size_t)px0 * kOutC;
      const float* c1 = ctx_t + (size_t)px1 * kOutC;
      const float* c2 = ctx_t + (size_t)px2 * kOutC;
      const float* c3 = ctx_t + (size_t)px3 * kOutC;
      a0 = fmaf(w0, c0[lane], a0);
      a0 = fmaf(w1, c1[lane], a0);
      a0 = fmaf(w2, c2[lane], a0);
      a0 = fmaf(w3, c3[lane], a0);
      if (lane < 16) {
        a1 = fmaf(w0, c0[64 + lane], a1);
        a1 = fmaf(w1, c1[64 + lane], a1);
        a1 = fmaf(w2, c2[64 + lane], a1);
        a1 = fmaf(w3, c3[64 + lane], a1);
      }
      e += 4;
    } else {
      const int ve = evox[e];
      if (ve != v) {
        float* pp = pooled + (size_t)v * kOutC;
        atomicAdd(pp + lane, a0);
        if (lane < 16) atomicAdd(pp + 64 + lane, a1);
        v = ve;
        a0 = 0.f;
        a1 = 0.f;
      } else {
        const int px = epix[e];
        const float w0 = ew[e];
        const float* cp = ctx_t + (size_t)px * kOutC;
        a0 = fmaf(w0, cp[lane], a0);
        if (lane < 16) a1 = fmaf(w0, cp[64 + lane], a1);
        ++e;
      }
    }
  }
  float* pp = pooled + (size_t)v * kOutC;
  atomicAdd(pp + lane, a0);
  if (lane < 16) atomicAdd(pp + 64 + lane, a1);
}

// ---------------- pooled [vox][c] -> bev PADDED [c][362][364] ----------------
__global__ __launch_bounds__(256) void pool_transpose_kernel(
    const float* __restrict__ pooled, float* __restrict__ bev) {
  __shared__ float t[32][kOutC + 1];
  const int tid = threadIdx.x;
  const int s0 = blockIdx.x * 32;
  for (int e = tid; e < 32 * kOutC; e += 256) {
    const int r = e / kOutC;
    const int c = e - r * kOutC;
    t[r][c] = pooled[(size_t)(s0 + r) * kOutC + c];
  }
  __syncthreads();
  for (int e = tid; e < 32 * kOutC; e += 256) {
    const int c = e >> 5;
    const int r = e & 31;
    const int vox = s0 + r;
    const int gx = vox / kNX;
    const int gy = vox - gx * kNX;
    bev[((size_t)c * 362 + gx + 1) * 364 + gy + 1] = t[r][c];
  }
}

// ---------------- 3x3 conv + BN + ReLU, v9/v11 family ----------------
// XSWZ groups the NZ z-replicas of each tile on one XCD (L2-coalesced
// staging, measured FETCH 237->53MB). conv1 PX=8 (r19: 245->217us, +VALU
// 53->60%); conv3 this round: OCB 4->8 / NZ 20->10 (same barrier-
// amortization lever, bijective 720 = 8 x 90, t in 0..71 = exactly 72
// tiles). ic ascends 0..79 per output fmaf chain -> bit-identical.
template <int TW, int TH, int PX, int OCB, int ICC, int NZ, int TXT,
          int MINW, bool DEIOUT>
__global__ __launch_bounds__(256, MINW) void conv_s1_v9_kernel(
    const float* __restrict__ in, const int inRS, const int inPR,
    const float* __restrict__ wgt,
    const float* __restrict__ bng, const float* __restrict__ bnb,
    const float* __restrict__ bnm, const float* __restrict__ bnv,
    float* __restrict__ out, const int OHW) {
  constexpr int OTH = TH * PX;
  constexpr int ITH = OTH + 2;
  constexpr int LDSW = TW + 4;          // staged width (36 for TW=32)
  constexpr int CPR = LDSW / 4;         // chunks per row
  constexpr int CHUNKS = ICC * ITH * CPR;
  constexpr int PASSES = (CHUNKS + 255) / 256;
  constexpr int NCH = kOutC / ICC;
  constexpr int RH = PX + 2;
  __shared__ float lds[ICC * ITH * LDSW];
  const int tid = threadIdx.x;
  // XCD z-group swizzle: grid = 8 * (NZ * ntiles/8); tile t's NZ replicas
  // land on XCD t%8 at consecutive slots.
  const int wg = blockIdx.x;
  const int xcd = wg & 7;
  const int q = wg >> 3;
  const int bz = q % NZ;
  const int t = xcd + 8 * (q / NZ);
  const int bx = t % TXT;
  const int by = t / TXT;
  const int tx = tid % TW;
  const int ty = tid / TW;
  const int ox0 = min(TW * bx, OHW - TW);
  const int oy0 = min(OTH * by, OHW - OTH);
  const int oc0 = bz * OCB;

  float acc[PX][OCB];
#pragma unroll
  for (int p = 0; p < PX; ++p)
#pragma unroll
    for (int j = 0; j < OCB; ++j) acc[p][j] = 0.f;

  for (int c = 0; c < NCH; ++c) {
    const int icb = c * ICC;
    if (c) __syncthreads();
#pragma unroll
    for (int s = 0; s < PASSES; ++s) {
      const int j = tid + s * 256;
      if (j < CHUNKS) {
        const int r = j / CPR;
        const int k = j - r * CPR;
        const int ic = r / ITH;
        const int rr = r - ic * ITH;
        gload16(in + ((size_t)(icb + ic) * inPR + (oy0 + rr)) * inRS + ox0 + k * 4,
                lds + (size_t)j * 4);
      }
    }
    __syncthreads();
#pragma unroll 2
    for (int ii = 0; ii < ICC; ++ii) {
      float xr[RH][3];
#pragma unroll
      for (int m = 0; m < RH; ++m) {
        const int rb = (ii * ITH + ty * PX + m) * LDSW + tx;
        xr[m][0] = lds[rb];
        xr[m][1] = lds[rb + 1];
        xr[m][2] = lds[rb + 2];
      }
      const float* wb = wgt + ((size_t)oc0 * kOutC + (icb + ii)) * 9;
#pragma unroll
      for (int jj = 0; jj < OCB; ++jj) {
        const float* wj = wb + (size_t)jj * kOutC * 9;  // uniform -> s_load
#pragma unroll
        for (int dy = 0; dy < 3; ++dy)
#pragma unroll
          for (int dx = 0; dx < 3; ++dx) {
            const float wv = wj[dy * 3 + dx];
#pragma unroll
            for (int p = 0; p < PX; ++p)
              acc[p][jj] = fmaf(wv, xr[p + dy][dx], acc[p][jj]);
          }
      }
    }
  }

#pragma unroll
  for (int jj = 0; jj < OCB; ++jj) {
    const int oc = oc0 + jj;
    const float inv = 1.0f / sqrtf(bnv[oc] + 1e-5f);
    const float sc = bng[oc] * inv;
    const float mb = bnm[oc];
    const float bb = bnb[oc];
#pragma unroll
    for (int p = 0; p < PX; ++p) {
      const int oy = oy0 + ty * PX + p;
      const int ox = ox0 + tx;
      const float val = fmaxf((acc[p][jj] - mb) * sc + bb, 0.f);
      if (DEIOUT) {
        out[(((size_t)oc * 2 + (ox & 1)) * 362 + (oy + 1)) * 184 + (ox >> 1) + 1] = val;
      } else {
        out[((size_t)oc * OHW + oy) * OHW + ox] = val;
      }
    }
  }
}

// ---------------- conv2 v9: stride-2 dei input, thin-oc grid + XSWZ ----------------
// r16-best config: OCB=8, ICC=4, NZ=10 -> 720 blocks.
template <int OCB, int ICC, int NZ, int MINW>
__global__ __launch_bounds__(256, MINW) void conv2_dei_v9_kernel(
    const float* __restrict__ y1, const float* __restrict__ wgt,
    const float* __restrict__ bng, const float* __restrict__ bnb,
    const float* __restrict__ bnm, const float* __restrict__ bnv,
    float* __restrict__ y2) {   // padded [80][182][184]
  constexpr int TW = 16, TH = 16, PX = 2;
  constexpr int ITH = 65;
  constexpr int LDSW = 44;      // h0: 0..19, h1: 20..39, 40..43 unused
  constexpr int CPR = 11;
  constexpr int CHUNKS = ICC * ITH * CPR;
  constexpr int PASSES = (CHUNKS + 255) / 256;
  constexpr int NCH = kOutC / ICC;
  __shared__ float lds[ICC * ITH * LDSW];
  const int tid = threadIdx.x;
  const int wg = blockIdx.x;            // 720 = 8 * (NZ * 72 / 8)
  const int xcd = wg & 7;
  const int q = wg >> 3;
  const int bz = q % NZ;
  const int t = xcd + 8 * (q / NZ);
  const int bx = t % 12;                // 0..11
  const int by = t / 12;                // 0..5
  const int tx = tid % TW;
  const int ty = tid / TW;
  const int ox0 = min(16 * bx, 180 - 16);
  const int oy0 = min(32 * by, 180 - 32);
  const int Y0 = 2 * oy0;               // padded y1 row base
  const int oc0 = bz * OCB;

  float acc[PX][OCB];
#pragma unroll
  for (int p = 0; p < PX; ++p)
#pragma unroll
    for (int j = 0; j < OCB; ++j) acc[p][j] = 0.f;

  for (int c = 0; c < NCH; ++c) {
    const int icb = c * ICC;
    if (c) __syncthreads();
#pragma unroll
    for (int s = 0; s < PASSES; ++s) {
      const int j = tid + s * 256;
      if (j < CHUNKS) {
        const int r = j / CPR;
        const int k = j - r * CPR;
        const int ic = r / ITH;
        const int rr = r - ic * ITH;
        const int h = (k >= 5) ? 1 : 0;
        int kk = h ? (k - 5) : k;
        if (kk > 4) kk = 4;   // pad chunk 10: dup h1 seg 4 (in-bounds, unread)
        gload16(y1 + (((size_t)(icb + ic) * 2 + h) * 362 + (Y0 + rr)) * 184 + ox0 + kk * 4,
                lds + (size_t)j * 4);
      }
    }
    __syncthreads();
#pragma unroll 2
    for (int ii = 0; ii < ICC; ++ii) {
      float xr[5][3];
#pragma unroll
      for (int m = 0; m < 5; ++m) {
        const int rb = (ii * ITH + 4 * ty + m) * LDSW;
        xr[m][0] = lds[rb + 20 + tx];   // dx=0 -> h1, u'=ox2
        xr[m][1] = lds[rb + tx + 1];    // dx=1 -> h0, u'=ox2+1
        xr[m][2] = lds[rb + 21 + tx];   // dx=2 -> h1, u'=ox2+1
      }
      const float* wb = wgt + ((size_t)oc0 * kOutC + (icb + ii)) * 9;
#pragma unroll
      for (int jj = 0; jj < OCB; ++jj) {
        const float* wj = wb + (size_t)jj * kOutC * 9;
#pragma unroll
        for (int dy = 0; dy < 3; ++dy)
#pragma unroll
          for (int dx = 0; dx < 3; ++dx) {
            const float wv = wj[dy * 3 + dx];
#pragma unroll
            for (int p = 0; p < PX; ++p)
              acc[p][jj] = fmaf(wv, xr[2 * p + dy][dx], acc[p][jj]);
          }
      }
    }
  }

#pragma unroll
  for (int jj = 0; jj < OCB; ++jj) {
    const int oc = oc0 + jj;
    const float inv = 1.0f / sqrtf(bnv[oc] + 1e-5f);
    const float sc = bng[oc] * inv;
    const float mb = bnm[oc];
    const float bb = bnb[oc];
#pragma unroll
    for (int p = 0; p < PX; ++p) {
      const int oy = oy0 + ty * PX + p;
      const int ox = ox0 + tx;
      const float val = fmaxf((acc[p][jj] - mb) * sc + bb, 0.f);
      y2[((size_t)oc * 182 + oy + 1) * 184 + ox + 1] = val;
    }
  }
}

// ---------------- final H<->W transpose of (80,180,180) ----------------
__global__ void transpose_out_kernel(const float* __restrict__ in,
                                     float* __restrict__ out) {
  __shared__ float t[32][33];
  const int c = blockIdx.z;
  const int i0 = blockIdx.y * 32;
  const int j0 = blockIdx.x * 32;
  const int tx = threadIdx.x;
  const int ty = threadIdx.y;
  const float* ip = in + (size_t)c * 180 * 180;
  float* op = out + (size_t)c * 180 * 180;
  for (int r = ty; r < 32; r += 8) {
    const int i = i0 + r, j = j0 + tx;
    t[r][tx] = (i < 180 && j < 180) ? ip[i * 180 + j] : 0.f;
  }
  __syncthreads();
  for (int r = ty; r < 32; r += 8) {
    const int j = j0 + r, i = i0 + tx;
    if (j < 180 && i < 180) op[j * 180 + i] = t[tx][r];
  }
}

}  // namespace

extern "C" void kernel_launch(void* const* d_in, const int* in_sizes, int n_in,
                              void* d_out, int out_size, void* d_ws, size_t ws_size,
                              hipStream_t stream) {
  const float* image = (const float*)d_in[0];
  const float* l2i   = (const float*)d_in[1];
  const float* aug   = (const float*)d_in[2];
  const float* dnw   = (const float*)d_in[3];
  const float* dnb   = (const float*)d_in[4];
  const float* c1w = (const float*)d_in[5];
  const float* b1g = (const float*)d_in[6];
  const float* b1b = (const float*)d_in[7];
  const float* b1m = (const float*)d_in[8];
  const float* b1v = (const float*)d_in[9];
  const float* c2w = (const float*)d_in[10];
  const float* b2g = (const float*)d_in[11];
  const float* b2b = (const float*)d_in[12];
  const float* b2m = (const float*)d_in[13];
  const float* b2v = (const float*)d_in[14];
  const float* c3w = (const float*)d_in[15];
  const float* b3g = (const float*)d_in[16];
  const float* b3b = (const float*)d_in[17];
  const float* b3m = (const float*)d_in[18];
  const float* b3v = (const float*)d_in[19];
  float* out = (float*)d_out;

  // Workspace layout (peak ~100 MiB):
  //  A [0,14MiB):   feat (12.8MiB) -> y2 padded (10.2MiB) after fill
  //  B [14,58MiB):  pooled (39.6MiB) -> y1 dei (40.7MiB) -> y3 (9.9MiB)
  //  C [58MiB,..):  CSR scratch (ctx_t/pvox/epix/ew/smalls/wt_t/evox), then
  //                 bev padded (40.2MiB) after spmm (scratch dead)
  char* ws = (char*)d_ws;
  float*  feat   = (float*)(ws);
  float*  pooled = (float*)(ws + ((size_t)14 << 20));
  float*  ctx_t     = (float*)(ws + ((size_t)58 << 20));
  int*    point_vox = (int*)(ws + ((size_t)64 << 20));
  int*    epix      = (int*)(ws + ((size_t)72 << 20));
  float*  ew        = (float*)(ws + ((size_t)80 << 20));
  int*    counts  = (int*)(ws + ((size_t)88 << 20));
  int*    offsets = (int*)(ws + ((size_t)88 << 20) + 600000);
  int*    cursor  = (int*)(ws + ((size_t)88 << 20) + 1200000);
  int*    bsums   = (int*)(ws + ((size_t)88 << 20) + 1800000);
  double* invm    = (double*)(ws + ((size_t)88 << 20) + 1900000);
  float*  wt_t    = (float*)(ws + ((size_t)90 << 20));
  int*    evox    = (int*)(ws + ((size_t)92 << 20));    // 8.0 MB
  float*  bev    = (float*)(ws + ((size_t)58 << 20));   // after scratch dies
  float*  y1 = pooled;                                   // dei [80][2][362][184]
  float*  y2 = feat;                                     // padded [80][182][184]
  float*  y3 = pooled;                                   // [80][180][180]

  const size_t bevBytes  = (size_t)kOutC * 362 * 364 * 4;      // 42,165,760
  const size_t y1Bytes   = (size_t)kOutC * 2 * 362 * 184 * 4;  // 42,629,120
  const size_t y2Bytes   = (size_t)kOutC * 182 * 184 * 4;      // 10,716,160
  const size_t poolBytes = (size_t)kNVox * kOutC * 4;          // 41,472,000

  prep_inverses_kernel<<<1, 64, 0, stream>>>(aug, l2i, invm);
  wt_transpose_kernel<<<208, 256, 0, stream>>>(dnw, wt_t);
  depthnet_v3_kernel<<<dim3(kNPix / 512, 13), 256, 0, stream>>>(image, wt_t, dnb, feat);
  softmax_depth_kernel<<<kNPix / 256, 256, 0, stream>>>(feat);
  ctx_transpose_kernel<<<kNPix / 32, 256, 0, stream>>>(feat, ctx_t);

  hipMemsetAsync(counts, 0, (size_t)kNVox * sizeof(int), stream);
  point_bin_kernel<<<kNPts / 256, 256, 0, stream>>>(invm, point_vox, counts);
  scan_k1<<<kScanB, 256, 0, stream>>>(counts, offsets, bsums);
  scan_k2<<<1, 64, 0, stream>>>(bsums, offsets);
  scan_k3<<<kScanB, 256, 0, stream>>>(offsets, bsums, cursor);
  fill_kernel<<<kNPts / 256, 256, 0, stream>>>(point_vox, cursor, feat, epix, ew, evox);
  hipMemsetAsync(pooled, 0, poolBytes, stream);
  spmm_seg_kernel<<<(kMaxSeg + 3) / 4, 256, 0, stream>>>(offsets, evox, epix, ew,
                                                         ctx_t, pooled);

  hipMemsetAsync(bev, 0, bevBytes, stream);                 // scratch dead
  pool_transpose_kernel<<<kNVox / 32, 256, 0, stream>>>(pooled, bev);
  hipMemsetAsync(y1, 0, y1Bytes, stream);                   // pooled dead

  // conv1 (r19-best): 32x64 tile (PX=8), OCB=8, ICC=4 (LDS 38KB), NZ=10 ->
  // 720 blocks; measured 217us / VALUBusy 60%.
  conv_s1_v9_kernel<32, 8, 8, 8, 4, 10, 12, 3, true>
      <<<720, 256, 0, stream>>>(bev, 364, 362, c1w,
                                b1g, b1b, b1m, b1v, y1, 360);
  hipMemsetAsync(y2, 0, y2Bytes, stream);                   // feat dead
  // conv2 (r16-best): dei input, OCB=8, ICC=4, NZ=10 -> 720 blocks.
  conv2_dei_v9_kernel<8, 4, 10, 3>
      <<<720, 256, 0, stream>>>(y1, c2w, b2g, b2b, b2m, b2v, y2);
  // conv3 v12: 180^2, 32x16 tile, OCB=8, ICC=4, NZ=10 -> 720 blocks
  // (bijective: 72 tiles x 10 = 720 = 8x90). Doubles per-chunk FMA vs the
  // r16 OCB=4 config; halves staging replication (NZ 20->10).
  conv_s1_v9_kernel<32, 8, 2, 8, 4, 10, 6, 4, false>
      <<<720, 256, 0, stream>>>(y2, 184, 182, c3w,
                                b3g, b3b, b3m, b3v, y3, 180);

  transpose_out_kernel<<<dim3(6, 6, 80), dim3(32, 8), 0, stream>>>(y3, out);
}

// Round 21
// 846.508 us; speedup vs baseline: 1.0277x; 1.0277x over previous
//
#include <hip/hip_runtime.h>
#include <math.h>
#include <stdint.h>

namespace {

constexpr int kNCam  = 6;
constexpr int kInCh  = 256;
constexpr int kOutC  = 80;
constexpr int kDB    = 118;   // depth bins
constexpr int kFH    = 32;
constexpr int kFW    = 88;
constexpr int kHW    = kFH * kFW;       // 2816
constexpr int kNPix  = kNCam * kHW;     // 16896
constexpr int kFeatC = kDB + kOutC;     // 198
constexpr int kNX    = 360;
constexpr int kNVox  = kNX * kNX;       // 129600
constexpr int kNPts  = kDB * kNPix;     // 1993728
constexpr int kScanB = (kNVox + 1023) / 1024;  // 127
constexpr int kSegE  = 256;             // entries per SpMM segment-wave
constexpr int kMaxSeg = (kNPts + kSegE - 1) / kSegE;  // 7788

// async global->LDS DMA, 16B per lane. LDS dest must be linear in lane
// (base + lane*16); global src is per-lane. CK-style addrspace casts.
__device__ __forceinline__ void gload16(const float* g, float* l) {
  auto* gg = reinterpret_cast<const __attribute__((address_space(1))) float*>(
      reinterpret_cast<uintptr_t>(g));
  auto* ll = reinterpret_cast<__attribute__((address_space(3))) float*>(
      reinterpret_cast<uintptr_t>(l));
  __builtin_amdgcn_global_load_lds(gg, ll, 16, 0, 0);
}

// ---------------- 4x4 matrix inverses (fp64 cofactor) ----------------
// Geometry decision path is kept ENTIRELY in fp64; passed with absmax 0.0332.
// DO NOT change anything in the geometry/binning path.
__global__ void prep_inverses_kernel(const float* __restrict__ aug,
                                     const float* __restrict__ l2i,
                                     double* __restrict__ invm) {
  const int t = threadIdx.x;
  if (t >= 12) return;
  const float* s = (t < 6) ? (aug + t * 16) : (l2i + (t - 6) * 16);
  double m[16];
#pragma unroll
  for (int i = 0; i < 16; ++i) m[i] = (double)s[i];
  double inv[16];
  inv[0]  =  m[5]*m[10]*m[15] - m[5]*m[11]*m[14] - m[9]*m[6]*m[15] + m[9]*m[7]*m[14] + m[13]*m[6]*m[11] - m[13]*m[7]*m[10];
  inv[4]  = -m[4]*m[10]*m[15] + m[4]*m[11]*m[14] + m[8]*m[6]*m[15] - m[8]*m[7]*m[14] - m[12]*m[6]*m[11] + m[12]*m[7]*m[10];
  inv[8]  =  m[4]*m[9]*m[15]  - m[4]*m[11]*m[13] - m[8]*m[5]*m[15] + m[8]*m[7]*m[13] + m[12]*m[5]*m[11] - m[12]*m[7]*m[9];
  inv[12] = -m[4]*m[9]*m[14]  + m[4]*m[10]*m[13] + m[8]*m[5]*m[14] - m[8]*m[6]*m[13] - m[12]*m[5]*m[10] + m[12]*m[6]*m[9];
  inv[1]  = -m[1]*m[10]*m[15] + m[1]*m[11]*m[14] + m[9]*m[2]*m[15] - m[9]*m[3]*m[14] - m[13]*m[2]*m[11] + m[13]*m[3]*m[10];
  inv[5]  =  m[0]*m[10]*m[15] - m[0]*m[11]*m[14] - m[8]*m[2]*m[15] + m[8]*m[3]*m[14] + m[12]*m[2]*m[11] - m[12]*m[3]*m[10];
  inv[9]  = -m[0]*m[9]*m[15]  + m[0]*m[11]*m[13] + m[8]*m[1]*m[15] - m[8]*m[3]*m[13] - m[12]*m[1]*m[11] + m[12]*m[3]*m[9];
  inv[13] =  m[0]*m[9]*m[14]  - m[0]*m[10]*m[13] - m[8]*m[1]*m[14] + m[8]*m[2]*m[13] + m[12]*m[1]*m[10] - m[12]*m[2]*m[9];
  inv[2]  =  m[1]*m[6]*m[15]  - m[1]*m[7]*m[14]  - m[5]*m[2]*m[15] + m[5]*m[3]*m[14] + m[13]*m[2]*m[7]  - m[13]*m[3]*m[6];
  inv[6]  = -m[0]*m[6]*m[15]  + m[0]*m[7]*m[14]  + m[4]*m[2]*m[15] - m[4]*m[3]*m[14] - m[12]*m[2]*m[7]  + m[12]*m[3]*m[6];
  inv[10] =  m[0]*m[5]*m[15]  - m[0]*m[7]*m[13]  - m[4]*m[1]*m[15] + m[4]*m[3]*m[13] + m[12]*m[1]*m[7]  - m[12]*m[3]*m[5];
  inv[14] = -m[0]*m[5]*m[14]  + m[0]*m[6]*m[13]  + m[4]*m[1]*m[14] - m[4]*m[2]*m[13] - m[12]*m[1]*m[6]  + m[12]*m[2]*m[5];
  inv[3]  = -m[1]*m[6]*m[11]  + m[1]*m[7]*m[10]  + m[5]*m[2]*m[11] - m[5]*m[3]*m[10] - m[9]*m[2]*m[7]   + m[9]*m[3]*m[6];
  inv[7]  =  m[0]*m[6]*m[11]  - m[0]*m[7]*m[10]  - m[4]*m[2]*m[11] + m[4]*m[3]*m[10] + m[8]*m[2]*m[7]   - m[8]*m[3]*m[6];
  inv[11] = -m[0]*m[5]*m[11]  + m[0]*m[7]*m[9]   + m[4]*m[1]*m[11] - m[4]*m[3]*m[9]  - m[8]*m[1]*m[7]   + m[8]*m[3]*m[5];
  inv[15] =  m[0]*m[5]*m[10]  - m[0]*m[6]*m[9]   - m[4]*m[1]*m[10] + m[4]*m[2]*m[9]  + m[8]*m[1]*m[6]   - m[8]*m[2]*m[5];
  const double det = m[0]*inv[0] + m[1]*inv[4] + m[2]*inv[8] + m[3]*inv[12];
  const double id = 1.0 / det;
#pragma unroll
  for (int i = 0; i < 16; ++i) invm[(size_t)t * 16 + i] = inv[i] * id;
}

// ---------------- depthnet weight transpose: wt_t[ic][208] ----------------
__global__ __launch_bounds__(256) void wt_transpose_kernel(
    const float* __restrict__ w, float* __restrict__ wt_t) {
  const int i = blockIdx.x * 256 + threadIdx.x;
  if (i >= 256 * 208) return;
  const int ic = i / 208;
  const int oc = i - ic * 208;
  wt_t[i] = (oc < kFeatC) ? w[oc * kInCh + ic] : 0.f;
}

// ---------------- depthnet 1x1 conv, v3: gload_lds + OCB=16 ----------------
// Summation order per output: ic ascending, fmaf chain -> bit-identical.
__global__ __launch_bounds__(256, 4) void depthnet_v3_kernel(
    const float* __restrict__ img, const float* __restrict__ wt_t,
    const float* __restrict__ bias, float* __restrict__ feat) {
  __shared__ float xs[16 * 512];
  const int tid = threadIdx.x;
  const int p0 = blockIdx.x * 512;       // kNPix % 512 == 0 (33 blocks)
  const int oc0 = blockIdx.y * 16;
  float acc[2][16];
#pragma unroll
  for (int h = 0; h < 2; ++h)
#pragma unroll
    for (int j = 0; j < 16; ++j) acc[h][j] = 0.f;
  for (int ic0 = 0; ic0 < kInCh; ic0 += 16) {
    if (ic0) __syncthreads();
#pragma unroll
    for (int s = 0; s < 8; ++s) {          // 2048 chunks of 16B
      const int j = tid + s * 256;
      const int r = j >> 7;                // 128 chunks per ic row
      const int k = j & 127;
      const int p4 = p0 + k * 4;           // 4-aligned, never straddles a cam
      const int n = p4 / kHW;
      const int hw = p4 - n * kHW;
      gload16(img + ((size_t)(n * kInCh + ic0 + r)) * kHW + hw, &xs[j * 4]);
    }
    __syncthreads();
#pragma unroll
    for (int kk = 0; kk < 16; ++kk) {
      const float xv0 = xs[kk * 512 + tid];
      const float xv1 = xs[kk * 512 + tid + 256];
      const float* wr = wt_t + (size_t)(ic0 + kk) * 208 + oc0;
#pragma unroll
      for (int j = 0; j < 16; ++j) {
        const float wv = wr[j];
        acc[0][j] = fmaf(wv, xv0, acc[0][j]);
        acc[1][j] = fmaf(wv, xv1, acc[1][j]);
      }
    }
  }
#pragma unroll
  for (int hp = 0; hp < 2; ++hp) {
    const int p = p0 + tid + hp * 256;
    const int n = p / kHW;
    const int hw = p - n * kHW;
#pragma unroll
    for (int j = 0; j < 16; ++j) {
      const int oc = oc0 + j;
      if (oc < kFeatC)
        feat[((size_t)n * kFeatC + oc) * kHW + hw] = acc[hp][j] + bias[oc];
    }
  }
}

// ---------------- softmax over depth bins, in place ----------------
__global__ __launch_bounds__(256) void softmax_depth_kernel(float* __restrict__ feat) {
  const int p = blockIdx.x * 256 + threadIdx.x;
  const int n = p / kHW;
  const int hw = p - n * kHW;
  float* base = feat + (size_t)n * kFeatC * kHW + hw;
  float mx = -3.4e38f;
  for (int d = 0; d < kDB; ++d) mx = fmaxf(mx, base[(size_t)d * kHW]);
  float s = 0.f;
  for (int d = 0; d < kDB; ++d) s += expf(base[(size_t)d * kHW] - mx);
  for (int d = 0; d < kDB; ++d) {
    const float e = expf(base[(size_t)d * kHW] - mx);
    base[(size_t)d * kHW] = e / s;
  }
}

// ---------------- ctx -> pixel-major ctx_t[pix][80] ----------------
__global__ __launch_bounds__(256) void ctx_transpose_kernel(
    const float* __restrict__ feat, float* __restrict__ ctx_t) {
  __shared__ float t[32][81];
  const int tid = threadIdx.x;
  const int b0 = blockIdx.x * 32;
  for (int e = tid; e < 32 * kOutC; e += 256) {
    const int c = e >> 5;
    const int q = e & 31;
    const int pix = b0 + q;
    const int n = pix / kHW;
    const int hw = pix - n * kHW;
    t[q][c] = feat[((size_t)n * kFeatC + kDB + c) * kHW + hw];
  }
  __syncthreads();
  for (int e = tid; e < 32 * kOutC; e += 256) {
    const int q = e / kOutC;
    const int c = e - q * kOutC;
    ctx_t[(size_t)(b0 + q) * kOutC + c] = t[q][c];
  }
}

// ---------------- pass A: per-point voxel binning + histogram ----------------
// fp64 chain copied VERBATIM from the passing kernel.
__global__ __launch_bounds__(256) void point_bin_kernel(
    const double* __restrict__ invm, int* __restrict__ point_vox,
    int* __restrict__ counts) {
  const int p = blockIdx.x * 256 + threadIdx.x;
  const int dd = p / kNPix;
  const int pix = p - dd * kNPix;
  const int n = pix / kHW;
  const int hw = pix - n * kHW;
  const int h = hw / kFW;
  const int w = hw - h * kFW;
  const double* A = invm + (size_t)n * 16;
  const double* L = invm + 96 + (size_t)n * 16;
  const double x = (double)(float)((double)w * (703.0 / 87.0));
  const double y = (double)(float)((double)h * (255.0 / 31.0));
  const double d = (double)(1.0f + 0.5f * (float)dd);
  const double p0 = A[0] * x + A[1] * y + A[2]  * d + A[3];
  const double p1 = A[4] * x + A[5] * y + A[6]  * d + A[7];
  const double p2 = A[8] * x + A[9] * y + A[10] * d + A[11];
  const double q0 = p0 * p2, q1 = p1 * p2;
  const double g0 = L[0] * q0 + L[1] * q1 + L[2]  * p2 + L[3];
  const double g1 = L[4] * q0 + L[5] * q1 + L[6]  * p2 + L[7];
  const double g2 = L[8] * q0 + L[9] * q1 + L[10] * p2 + L[11];
  const double off01 = (double)__fsub_rn(-53.85f, 0.15f);
  const double fx = (g0 - off01) / (double)0.3f;
  const double fy = (g1 - off01) / (double)0.3f;
  const double fz = (g2 - (double)(-10.0f)) / (double)20.0f;
  const int gx = (int)fx;
  const int gy = (int)fy;
  const int gz = (int)fz;
  int vox = -1;
  if (gx >= 0 && gx < kNX && gy >= 0 && gy < kNX && gz == 0)
    vox = gx * kNX + gy;
  point_vox[p] = vox;
  if (vox >= 0) atomicAdd(counts + vox, 1);
}

// ---------------- exclusive scan over voxel counts ----------------
__global__ __launch_bounds__(256) void scan_k1(const int* __restrict__ counts,
                                               int* __restrict__ offsets,
                                               int* __restrict__ bsums) {
  __shared__ int sh[256];
  const int t = threadIdx.x;
  const int base = blockIdx.x * 1024 + t * 4;
  int v[4];
  int s = 0;
#pragma unroll
  for (int k = 0; k < 4; ++k) {
    const int i = base + k;
    v[k] = (i < kNVox) ? counts[i] : 0;
    s += v[k];
  }
  sh[t] = s;
  __syncthreads();
  for (int ofs = 1; ofs < 256; ofs <<= 1) {
    const int x = (t >= ofs) ? sh[t - ofs] : 0;
    __syncthreads();
    sh[t] += x;
    __syncthreads();
  }
  const int excl = sh[t] - s;
  if (t == 255) bsums[blockIdx.x] = sh[255];
  int run = excl;
#pragma unroll
  for (int k = 0; k < 4; ++k) {
    const int i = base + k;
    if (i < kNVox) offsets[i] = run;
    run += v[k];
  }
}

__global__ void scan_k2(int* __restrict__ bsums, int* __restrict__ offsets) {
  if (threadIdx.x == 0) {
    int run = 0;
    for (int b = 0; b < kScanB; ++b) {
      const int x = bsums[b];
      bsums[b] = run;
      run += x;
    }
    offsets[kNVox] = run;
  }
}

__global__ __launch_bounds__(256) void scan_k3(int* __restrict__ offsets,
                                               const int* __restrict__ bsums,
                                               int* __restrict__ cursor) {
  const int base = blockIdx.x * 1024 + threadIdx.x * 4;
  const int add = bsums[blockIdx.x];
#pragma unroll
  for (int k = 0; k < 4; ++k) {
    const int i = base + k;
    if (i < kNVox) {
      const int o = offsets[i] + add;
      offsets[i] = o;
      cursor[i] = o;
    }
  }
}

// ---------------- pass B: fill CSR entries (+ per-entry voxel id) ----------------
__global__ __launch_bounds__(256) void fill_kernel(
    const int* __restrict__ point_vox, int* __restrict__ cursor,
    const float* __restrict__ feat, int* __restrict__ epix,
    float* __restrict__ ew, int* __restrict__ evox) {
  const int p = blockIdx.x * 256 + threadIdx.x;
  const int v = point_vox[p];
  if (v < 0) return;
  const int dd = p / kNPix;
  const int pix = p - dd * kNPix;
  const int n = pix / kHW;
  const int hw = pix - n * kHW;
  const int pos = atomicAdd(cursor + v, 1);
  epix[pos] = pix;
  ew[pos] = feat[((size_t)n * kFeatC + dd) * kHW + hw];
  evox[pos] = v;
}

// ---------------- segmented SpMM: one wave per 256-entry segment ----------------
__global__ __launch_bounds__(256) void spmm_seg_kernel(
    const int* __restrict__ off, const int* __restrict__ evox,
    const int* __restrict__ epix, const float* __restrict__ ew,
    const float* __restrict__ ctx_t, float* __restrict__ pooled) {
  const int wid = (blockIdx.x * 256 + threadIdx.x) >> 6;
  const int lane = threadIdx.x & 63;
  const int nnz = off[kNVox];
  const int s0 = wid * kSegE;
  if (s0 >= nnz) return;
  const int s1 = min(s0 + kSegE, nnz);
  int e = s0;
  int v = evox[e];
  float a0 = 0.f, a1 = 0.f;
  while (e < s1) {
    if (e + 3 < s1 && evox[e + 3] == v) {   // non-decreasing -> e..e+3 all v
      const int px0 = epix[e], px1 = epix[e + 1];
      const int px2 = epix[e + 2], px3 = epix[e + 3];
      const float w0 = ew[e], w1 = ew[e + 1], w2 = ew[e + 2], w3 = ew[e + 3];
      const float* c0 = ctx_t + (size_t)px0 * kOutC;
      const float* c1 = ctx_t + (size_t)px1 * kOutC;
      const float* c2 = ctx_t + (size_t)px2 * kOutC;
      const float* c3 = ctx_t + (size_t)px3 * kOutC;
      a0 = fmaf(w0, c0[lane], a0);
      a0 = fmaf(w1, c1[lane], a0);
      a0 = fmaf(w2, c2[lane], a0);
      a0 = fmaf(w3, c3[lane], a0);
      if (lane < 16) {
        a1 = fmaf(w0, c0[64 + lane], a1);
        a1 = fmaf(w1, c1[64 + lane], a1);
        a1 = fmaf(w2, c2[64 + lane], a1);
        a1 = fmaf(w3, c3[64 + lane], a1);
      }
      e += 4;
    } else {
      const int ve = evox[e];
      if (ve != v) {
        float* pp = pooled + (size_t)v * kOutC;
        atomicAdd(pp + lane, a0);
        if (lane < 16) atomicAdd(pp + 64 + lane, a1);
        v = ve;
        a0 = 0.f;
        a1 = 0.f;
      } else {
        const int px = epix[e];
        const float w0 = ew[e];
        const float* cp = ctx_t + (size_t)px * kOutC;
        a0 = fmaf(w0, cp[lane], a0);
        if (lane < 16) a1 = fmaf(w0, cp[64 + lane], a1);
        ++e;
      }
    }
  }
  float* pp = pooled + (size_t)v * kOutC;
  atomicAdd(pp + lane, a0);
  if (lane < 16) atomicAdd(pp + 64 + lane, a1);
}

// ---------------- pooled [vox][c] -> bev PADDED [c][362][364] ----------------
__global__ __launch_bounds__(256) void pool_transpose_kernel(
    const float* __restrict__ pooled, float* __restrict__ bev) {
  __shared__ float t[32][kOutC + 1];
  const int tid = threadIdx.x;
  const int s0 = blockIdx.x * 32;
  for (int e = tid; e < 32 * kOutC; e += 256) {
    const int r = e / kOutC;
    const int c = e - r * kOutC;
    t[r][c] = pooled[(size_t)(s0 + r) * kOutC + c];
  }
  __syncthreads();
  for (int e = tid; e < 32 * kOutC; e += 256) {
    const int c = e >> 5;
    const int r = e & 31;
    const int vox = s0 + r;
    const int gx = vox / kNX;
    const int gy = vox - gx * kNX;
    bev[((size_t)c * 362 + gx + 1) * 364 + gy + 1] = t[r][c];
  }
}

// ---------------- 3x3 conv + BN + ReLU, v9/v11 family (r19-best configs) ----------------
// XSWZ groups the NZ z-replicas of each tile on one XCD (L2-coalesced
// staging, measured FETCH 237->53MB). conv1 PX=8 (measured 217us,
// VALUBusy 60%); conv3 r19-best thin config (OCB=4/ICC=8/NZ=20; the
// r20 OCB=8 variant measured -23us net -> reverted). ic ascends 0..79
// per output fmaf chain -> bit-identical numerics.
template <int TW, int TH, int PX, int OCB, int ICC, int NZ, int TXT,
          int MINW, bool DEIOUT>
__global__ __launch_bounds__(256, MINW) void conv_s1_v9_kernel(
    const float* __restrict__ in, const int inRS, const int inPR,
    const float* __restrict__ wgt,
    const float* __restrict__ bng, const float* __restrict__ bnb,
    const float* __restrict__ bnm, const float* __restrict__ bnv,
    float* __restrict__ out, const int OHW) {
  constexpr int OTH = TH * PX;
  constexpr int ITH = OTH + 2;
  constexpr int LDSW = TW + 4;          // staged width (36 for TW=32)
  constexpr int CPR = LDSW / 4;         // chunks per row
  constexpr int CHUNKS = ICC * ITH * CPR;
  constexpr int PASSES = (CHUNKS + 255) / 256;
  constexpr int NCH = kOutC / ICC;
  constexpr int RH = PX + 2;
  __shared__ float lds[ICC * ITH * LDSW];
  const int tid = threadIdx.x;
  // XCD z-group swizzle: grid = 8 * (NZ * ntiles/8); tile t's NZ replicas
  // land on XCD t%8 at consecutive slots.
  const int wg = blockIdx.x;
  const int xcd = wg & 7;
  const int q = wg >> 3;
  const int bz = q % NZ;
  const int t = xcd + 8 * (q / NZ);
  const int bx = t % TXT;
  const int by = t / TXT;
  const int tx = tid % TW;
  const int ty = tid / TW;
  const int ox0 = min(TW * bx, OHW - TW);
  const int oy0 = min(OTH * by, OHW - OTH);
  const int oc0 = bz * OCB;

  float acc[PX][OCB];
#pragma unroll
  for (int p = 0; p < PX; ++p)
#pragma unroll
    for (int j = 0; j < OCB; ++j) acc[p][j] = 0.f;

  for (int c = 0; c < NCH; ++c) {
    const int icb = c * ICC;
    if (c) __syncthreads();
#pragma unroll
    for (int s = 0; s < PASSES; ++s) {
      const int j = tid + s * 256;
      if (j < CHUNKS) {
        const int r = j / CPR;
        const int k = j - r * CPR;
        const int ic = r / ITH;
        const int rr = r - ic * ITH;
        gload16(in + ((size_t)(icb + ic) * inPR + (oy0 + rr)) * inRS + ox0 + k * 4,
                lds + (size_t)j * 4);
      }
    }
    __syncthreads();
#pragma unroll 2
    for (int ii = 0; ii < ICC; ++ii) {
      float xr[RH][3];
#pragma unroll
      for (int m = 0; m < RH; ++m) {
        const int rb = (ii * ITH + ty * PX + m) * LDSW + tx;
        xr[m][0] = lds[rb];
        xr[m][1] = lds[rb + 1];
        xr[m][2] = lds[rb + 2];
      }
      const float* wb = wgt + ((size_t)oc0 * kOutC + (icb + ii)) * 9;
#pragma unroll
      for (int jj = 0; jj < OCB; ++jj) {
        const float* wj = wb + (size_t)jj * kOutC * 9;  // uniform -> s_load
#pragma unroll
        for (int dy = 0; dy < 3; ++dy)
#pragma unroll
          for (int dx = 0; dx < 3; ++dx) {
            const float wv = wj[dy * 3 + dx];
#pragma unroll
            for (int p = 0; p < PX; ++p)
              acc[p][jj] = fmaf(wv, xr[p + dy][dx], acc[p][jj]);
          }
      }
    }
  }

#pragma unroll
  for (int jj = 0; jj < OCB; ++jj) {
    const int oc = oc0 + jj;
    const float inv = 1.0f / sqrtf(bnv[oc] + 1e-5f);
    const float sc = bng[oc] * inv;
    const float mb = bnm[oc];
    const float bb = bnb[oc];
#pragma unroll
    for (int p = 0; p < PX; ++p) {
      const int oy = oy0 + ty * PX + p;
      const int ox = ox0 + tx;
      const float val = fmaxf((acc[p][jj] - mb) * sc + bb, 0.f);
      if (DEIOUT) {
        out[(((size_t)oc * 2 + (ox & 1)) * 362 + (oy + 1)) * 184 + (ox >> 1) + 1] = val;
      } else {
        out[((size_t)oc * OHW + oy) * OHW + ox] = val;
      }
    }
  }
}

// ---------------- conv2 v9: stride-2 dei input, thin-oc grid + XSWZ ----------------
// r16-best config: OCB=8, ICC=4, NZ=10 -> 720 blocks.
template <int OCB, int ICC, int NZ, int MINW>
__global__ __launch_bounds__(256, MINW) void conv2_dei_v9_kernel(
    const float* __restrict__ y1, const float* __restrict__ wgt,
    const float* __restrict__ bng, const float* __restrict__ bnb,
    const float* __restrict__ bnm, const float* __restrict__ bnv,
    float* __restrict__ y2) {   // padded [80][182][184]
  constexpr int TW = 16, TH = 16, PX = 2;
  constexpr int ITH = 65;
  constexpr int LDSW = 44;      // h0: 0..19, h1: 20..39, 40..43 unused
  constexpr int CPR = 11;
  constexpr int CHUNKS = ICC * ITH * CPR;
  constexpr int PASSES = (CHUNKS + 255) / 256;
  constexpr int NCH = kOutC / ICC;
  __shared__ float lds[ICC * ITH * LDSW];
  const int tid = threadIdx.x;
  const int wg = blockIdx.x;            // 720 = 8 * (NZ * 72 / 8)
  const int xcd = wg & 7;
  const int q = wg >> 3;
  const int bz = q % NZ;
  const int t = xcd + 8 * (q / NZ);
  const int bx = t % 12;                // 0..11
  const int by = t / 12;                // 0..5
  const int tx = tid % TW;
  const int ty = tid / TW;
  const int ox0 = min(16 * bx, 180 - 16);
  const int oy0 = min(32 * by, 180 - 32);
  const int Y0 = 2 * oy0;               // padded y1 row base
  const int oc0 = bz * OCB;

  float acc[PX][OCB];
#pragma unroll
  for (int p = 0; p < PX; ++p)
#pragma unroll
    for (int j = 0; j < OCB; ++j) acc[p][j] = 0.f;

  for (int c = 0; c < NCH; ++c) {
    const int icb = c * ICC;
    if (c) __syncthreads();
#pragma unroll
    for (int s = 0; s < PASSES; ++s) {
      const int j = tid + s * 256;
      if (j < CHUNKS) {
        const int r = j / CPR;
        const int k = j - r * CPR;
        const int ic = r / ITH;
        const int rr = r - ic * ITH;
        const int h = (k >= 5) ? 1 : 0;
        int kk = h ? (k - 5) : k;
        if (kk > 4) kk = 4;   // pad chunk 10: dup h1 seg 4 (in-bounds, unread)
        gload16(y1 + (((size_t)(icb + ic) * 2 + h) * 362 + (Y0 + rr)) * 184 + ox0 + kk * 4,
                lds + (size_t)j * 4);
      }
    }
    __syncthreads();
#pragma unroll 2
    for (int ii = 0; ii < ICC; ++ii) {
      float xr[5][3];
#pragma unroll
      for (int m = 0; m < 5; ++m) {
        const int rb = (ii * ITH + 4 * ty + m) * LDSW;
        xr[m][0] = lds[rb + 20 + tx];   // dx=0 -> h1, u'=ox2
        xr[m][1] = lds[rb + tx + 1];    // dx=1 -> h0, u'=ox2+1
        xr[m][2] = lds[rb + 21 + tx];   // dx=2 -> h1, u'=ox2+1
      }
      const float* wb = wgt + ((size_t)oc0 * kOutC + (icb + ii)) * 9;
#pragma unroll
      for (int jj = 0; jj < OCB; ++jj) {
        const float* wj = wb + (size_t)jj * kOutC * 9;
#pragma unroll
        for (int dy = 0; dy < 3; ++dy)
#pragma unroll
          for (int dx = 0; dx < 3; ++dx) {
            const float wv = wj[dy * 3 + dx];
#pragma unroll
            for (int p = 0; p < PX; ++p)
              acc[p][jj] = fmaf(wv, xr[2 * p + dy][dx], acc[p][jj]);
          }
      }
    }
  }

#pragma unroll
  for (int jj = 0; jj < OCB; ++jj) {
    const int oc = oc0 + jj;
    const float inv = 1.0f / sqrtf(bnv[oc] + 1e-5f);
    const float sc = bng[oc] * inv;
    const float mb = bnm[oc];
    const float bb = bnb[oc];
#pragma unroll
    for (int p = 0; p < PX; ++p) {
      const int oy = oy0 + ty * PX + p;
      const int ox = ox0 + tx;
      const float val = fmaxf((acc[p][jj] - mb) * sc + bb, 0.f);
      y2[((size_t)oc * 182 + oy + 1) * 184 + ox + 1] = val;
    }
  }
}

// ---------------- final H<->W transpose of (80,180,180) ----------------
__global__ void transpose_out_kernel(const float* __restrict__ in,
                                     float* __restrict__ out) {
  __shared__ float t[32][33];
  const int c = blockIdx.z;
  const int i0 = blockIdx.y * 32;
  const int j0 = blockIdx.x * 32;
  const int tx = threadIdx.x;
  const int ty = threadIdx.y;
  const float* ip = in + (size_t)c * 180 * 180;
  float* op = out + (size_t)c * 180 * 180;
  for (int r = ty; r < 32; r += 8) {
    const int i = i0 + r, j = j0 + tx;
    t[r][tx] = (i < 180 && j < 180) ? ip[i * 180 + j] : 0.f;
  }
  __syncthreads();
  for (int r = ty; r < 32; r += 8) {
    const int j = j0 + r, i = i0 + tx;
    if (j < 180 && i < 180) op[j * 180 + i] = t[tx][r];
  }
}

}  // namespace

extern "C" void kernel_launch(void* const* d_in, const int* in_sizes, int n_in,
                              void* d_out, int out_size, void* d_ws, size_t ws_size,
                              hipStream_t stream) {
  const float* image = (const float*)d_in[0];
  const float* l2i   = (const float*)d_in[1];
  const float* aug   = (const float*)d_in[2];
  const float* dnw   = (const float*)d_in[3];
  const float* dnb   = (const float*)d_in[4];
  const float* c1w = (const float*)d_in[5];
  const float* b1g = (const float*)d_in[6];
  const float* b1b = (const float*)d_in[7];
  const float* b1m = (const float*)d_in[8];
  const float* b1v = (const float*)d_in[9];
  const float* c2w = (const float*)d_in[10];
  const float* b2g = (const float*)d_in[11];
  const float* b2b = (const float*)d_in[12];
  const float* b2m = (const float*)d_in[13];
  const float* b2v = (const float*)d_in[14];
  const float* c3w = (const float*)d_in[15];
  const float* b3g = (const float*)d_in[16];
  const float* b3b = (const float*)d_in[17];
  const float* b3m = (const float*)d_in[18];
  const float* b3v = (const float*)d_in[19];
  float* out = (float*)d_out;

  // Workspace layout (peak ~100 MiB):
  //  A [0,14MiB):   feat (12.8MiB) -> y2 padded (10.2MiB) after fill
  //  B [14,58MiB):  pooled (39.6MiB) -> y1 dei (40.7MiB) -> y3 (9.9MiB)
  //  C [58MiB,..):  CSR scratch (ctx_t/pvox/epix/ew/smalls/wt_t/evox), then
  //                 bev padded (40.2MiB) after spmm (scratch dead)
  char* ws = (char*)d_ws;
  float*  feat   = (float*)(ws);
  float*  pooled = (float*)(ws + ((size_t)14 << 20));
  float*  ctx_t     = (float*)(ws + ((size_t)58 << 20));
  int*    point_vox = (int*)(ws + ((size_t)64 << 20));
  int*    epix      = (int*)(ws + ((size_t)72 << 20));
  float*  ew        = (float*)(ws + ((size_t)80 << 20));
  int*    counts  = (int*)(ws + ((size_t)88 << 20));
  int*    offsets = (int*)(ws + ((size_t)88 << 20) + 600000);
  int*    cursor  = (int*)(ws + ((size_t)88 << 20) + 1200000);
  int*    bsums   = (int*)(ws + ((size_t)88 << 20) + 1800000);
  double* invm    = (double*)(ws + ((size_t)88 << 20) + 1900000);
  float*  wt_t    = (float*)(ws + ((size_t)90 << 20));
  int*    evox    = (int*)(ws + ((size_t)92 << 20));    // 8.0 MB
  float*  bev    = (float*)(ws + ((size_t)58 << 20));   // after scratch dies
  float*  y1 = pooled;                                   // dei [80][2][362][184]
  float*  y2 = feat;                                     // padded [80][182][184]
  float*  y3 = pooled;                                   // [80][180][180]

  const size_t bevBytes  = (size_t)kOutC * 362 * 364 * 4;      // 42,165,760
  const size_t y1Bytes   = (size_t)kOutC * 2 * 362 * 184 * 4;  // 42,629,120
  const size_t y2Bytes   = (size_t)kOutC * 182 * 184 * 4;      // 10,716,160
  const size_t poolBytes = (size_t)kNVox * kOutC * 4;          // 41,472,000

  prep_inverses_kernel<<<1, 64, 0, stream>>>(aug, l2i, invm);
  wt_transpose_kernel<<<208, 256, 0, stream>>>(dnw, wt_t);
  depthnet_v3_kernel<<<dim3(kNPix / 512, 13), 256, 0, stream>>>(image, wt_t, dnb, feat);
  softmax_depth_kernel<<<kNPix / 256, 256, 0, stream>>>(feat);
  ctx_transpose_kernel<<<kNPix / 32, 256, 0, stream>>>(feat, ctx_t);

  hipMemsetAsync(counts, 0, (size_t)kNVox * sizeof(int), stream);
  point_bin_kernel<<<kNPts / 256, 256, 0, stream>>>(invm, point_vox, counts);
  scan_k1<<<kScanB, 256, 0, stream>>>(counts, offsets, bsums);
  scan_k2<<<1, 64, 0, stream>>>(bsums, offsets);
  scan_k3<<<kScanB, 256, 0, stream>>>(offsets, bsums, cursor);
  fill_kernel<<<kNPts / 256, 256, 0, stream>>>(point_vox, cursor, feat, epix, ew, evox);
  hipMemsetAsync(pooled, 0, poolBytes, stream);
  spmm_seg_kernel<<<(kMaxSeg + 3) / 4, 256, 0, stream>>>(offsets, evox, epix, ew,
                                                         ctx_t, pooled);

  hipMemsetAsync(bev, 0, bevBytes, stream);                 // scratch dead
  pool_transpose_kernel<<<kNVox / 32, 256, 0, stream>>>(pooled, bev);
  hipMemsetAsync(y1, 0, y1Bytes, stream);                   // pooled dead

  // conv1 (r19-best): 32x64 tile (PX=8), OCB=8, ICC=4 (LDS 38KB), NZ=10 ->
  // 720 blocks; measured 217us / VALUBusy 60%.
  conv_s1_v9_kernel<32, 8, 8, 8, 4, 10, 12, 3, true>
      <<<720, 256, 0, stream>>>(bev, 364, 362, c1w,
                                b1g, b1b, b1m, b1v, y1, 360);
  hipMemsetAsync(y2, 0, y2Bytes, stream);                   // feat dead
  // conv2 (r16-best): dei input, OCB=8, ICC=4, NZ=10 -> 720 blocks.
  conv2_dei_v9_kernel<8, 4, 10, 3>
      <<<720, 256, 0, stream>>>(y1, c2w, b2g, b2b, b2m, b2v, y2);
  // conv3 (r19-best): 180^2, 32x16 tile, OCB=4, ICC=8, NZ=20 -> 1440 blocks.
  conv_s1_v9_kernel<32, 8, 2, 4, 8, 20, 6, 4, false>
      <<<1440, 256, 0, stream>>>(y2, 184, 182, c3w,
                                 b3g, b3b, b3m, b3v, y3, 180);

  transpose_out_kernel<<<dim3(6, 6, 80), dim3(32, 8), 0, stream>>>(y3, out);
}